// Round 1
// baseline (2207.843 us; speedup 1.0000x reference)
//
#include <hip/hip_runtime.h>

typedef unsigned short u16;
using bf16x8 = __attribute__((ext_vector_type(8))) short;
using f32x4  = __attribute__((ext_vector_type(4))) float;

#define NN 50000
#define NPAD 50048

__device__ __forceinline__ u16 f2b(float f) {
  union { float f; unsigned u; } x; x.f = f;
  unsigned r = x.u + 0x7fffu + ((x.u >> 16) & 1u);
  return (u16)(r >> 16);
}
__device__ __forceinline__ float b2f(u16 h) {
  union { unsigned u; float f; } x; x.u = ((unsigned)h) << 16; return x.f;
}

#define GLOAD_LDS16(g, l) __builtin_amdgcn_global_load_lds( \
    (const __attribute__((address_space(1))) unsigned int*)(g), \
    (__attribute__((address_space(3))) unsigned int*)(l), 16, 0, 0)

// ---------------- CSR build ----------------
__global__ void hist_kernel(const int* __restrict__ rows, const float* __restrict__ vals,
                            int* __restrict__ counts, float* __restrict__ rowsum, int E) {
  int e = blockIdx.x * 256 + threadIdx.x;
  if (e < E) {
    int r = rows[e];
    atomicAdd(&counts[r], 1);
    atomicAdd(&rowsum[r], vals[e]);
  }
}

__global__ void scan_bsum(const int* __restrict__ counts, int* __restrict__ bsum, int n) {
  __shared__ int s[256];
  int t = threadIdx.x;
  int gi = blockIdx.x * 256 + t;
  s[t] = (gi < n) ? counts[gi] : 0;
  __syncthreads();
  for (int d = 128; d > 0; d >>= 1) {
    if (t < d) s[t] += s[t + d];
    __syncthreads();
  }
  if (t == 0) bsum[blockIdx.x] = s[0];
}

__global__ void scan_partials(int* __restrict__ bsum, int nb) {
  __shared__ int s[256];
  int t = threadIdx.x;
  int v = (t < nb) ? bsum[t] : 0;
  s[t] = v;
  __syncthreads();
  for (int d = 1; d < 256; d <<= 1) {
    int x = (t >= d) ? s[t - d] : 0;
    __syncthreads();
    s[t] += x;
    __syncthreads();
  }
  if (t < nb) bsum[t] = s[t] - v;  // exclusive
}

__global__ void scan_final(const int* __restrict__ counts, const int* __restrict__ bsum,
                           int* __restrict__ offs, int n) {
  __shared__ int s[256];
  int t = threadIdx.x;
  int gi = blockIdx.x * 256 + t;
  int v = (gi < n) ? counts[gi] : 0;
  s[t] = v;
  __syncthreads();
  for (int d = 1; d < 256; d <<= 1) {
    int x = (t >= d) ? s[t - d] : 0;
    __syncthreads();
    s[t] += x;
    __syncthreads();
  }
  if (gi <= n) offs[gi] = bsum[blockIdx.x] + s[t] - v;
}

__global__ void scatter_kernel(const int* __restrict__ rows, const int* __restrict__ cols,
                               const float* __restrict__ vals, const int* __restrict__ offs,
                               int* __restrict__ cursor, int* __restrict__ ecol,
                               float* __restrict__ ev2, int E) {
  int e = blockIdx.x * 256 + threadIdx.x;
  if (e < E) {
    int r = rows[e];
    int p = offs[r] + atomicAdd(&cursor[r], 1);
    ecol[p] = cols[e];
    ev2[p] = vals[e];
  }
}

// ---------------- conversions ----------------
__global__ void conv_f2b4(const float* __restrict__ in, u16* __restrict__ out, int n4) {
  int i = blockIdx.x * 256 + threadIdx.x;
  if (i < n4) {
    float4 f = ((const float4*)in)[i];
    ushort4 o;
    o.x = f2b(f.x); o.y = f2b(f.y); o.z = f2b(f.z); o.w = f2b(f.w);
    ((ushort4*)out)[i] = o;
  }
}

// W [K][N] f32 -> Wt [N][K] bf16
__global__ void transpose_conv(const float* __restrict__ W, u16* __restrict__ Wt, int K, int N) {
  __shared__ float tile[32][33];
  int bx = blockIdx.x * 32;  // n
  int by = blockIdx.y * 32;  // k
  int tx = threadIdx.x;
  int ty = threadIdx.y;
  for (int i = 0; i < 32; i += 8) tile[ty + i][tx] = W[(size_t)(by + ty + i) * N + bx + tx];
  __syncthreads();
  for (int i = 0; i < 32; i += 8) Wt[(size_t)(bx + ty + i) * K + by + tx] = f2b(tile[tx][ty + i]);
}

// ---------------- GEMM: C[M,N] = A[M,K] @ Bt[N,K]^T  (+bias, relu), bf16 in/out ----------------
__global__ __launch_bounds__(256)
void gemm_bt(const u16* __restrict__ A, const u16* __restrict__ Bt,
             const float* __restrict__ bias, const float* __restrict__ rowsum,
             u16* __restrict__ C, int M, int N, int K, int relu) {
  __shared__ u16 As[128 * 32];
  __shared__ u16 Bs[128 * 32];
  const int tid = threadIdx.x;
  const int lane = tid & 63;
  const int wave = tid >> 6;
  const int wm = wave >> 1;
  const int wn = wave & 1;
  const int bm = blockIdx.x * 128;
  const int bn = blockIdx.y * 128;
  const int l15 = lane & 15;
  const int lg = lane >> 4;

  f32x4 acc[4][4];
#pragma unroll
  for (int i = 0; i < 4; i++)
#pragma unroll
    for (int j = 0; j < 4; j++)
#pragma unroll
      for (int k = 0; k < 4; k++) acc[i][j][k] = 0.f;

  const int r = tid >> 2;          // 0..63
  const int c = (tid & 3) << 3;    // 0,8,16,24
  const u16* gA = A + (size_t)(bm + r) * K + c;
  const u16* gB = Bt + (size_t)(bn + r) * K + c;
  u16* lA = &As[r * 32 + c];
  u16* lB = &Bs[r * 32 + c];

  for (int k0 = 0; k0 < K; k0 += 32) {
    GLOAD_LDS16(gA, lA);
    GLOAD_LDS16(gA + (size_t)64 * K, lA + 64 * 32);
    GLOAD_LDS16(gB, lB);
    GLOAD_LDS16(gB + (size_t)64 * K, lB + 64 * 32);
    gA += 32;
    gB += 32;
    __syncthreads();
    bf16x8 af[4], bfr[4];
#pragma unroll
    for (int i = 0; i < 4; i++) af[i] = *(const bf16x8*)&As[(wm * 64 + i * 16 + l15) * 32 + lg * 8];
#pragma unroll
    for (int j = 0; j < 4; j++) bfr[j] = *(const bf16x8*)&Bs[(wn * 64 + j * 16 + l15) * 32 + lg * 8];
#pragma unroll
    for (int i = 0; i < 4; i++)
#pragma unroll
      for (int j = 0; j < 4; j++)
        acc[i][j] = __builtin_amdgcn_mfma_f32_16x16x32_bf16(af[i], bfr[j], acc[i][j], 0, 0, 0);
    __syncthreads();
  }

#pragma unroll
  for (int i = 0; i < 4; i++) {
    int row0 = bm + wm * 64 + i * 16 + lg * 4;
#pragma unroll
    for (int rr = 0; rr < 4; rr++) {
      int row = row0 + rr;
      if (row < M) {
        float rs = rowsum ? rowsum[row] : 1.0f;
#pragma unroll
        for (int j = 0; j < 4; j++) {
          int col = bn + wn * 64 + j * 16 + l15;
          float v = acc[i][j][rr] + rs * bias[col];
          if (relu) v = fmaxf(v, 0.f);
          C[(size_t)row * N + col] = f2b(v);
        }
      }
    }
  }
}

// ---------------- SpMM (CSR): out[i,:] = sum_e val[e] * X[col[e],:] ----------------
template <int VEC, int RELU, int OUTF32>
__global__ __launch_bounds__(256)
void spmm(const int* __restrict__ offs, const int* __restrict__ ecol,
          const float* __restrict__ ev, const u16* __restrict__ X,
          void* __restrict__ outp, int dcols) {
  const int node = blockIdx.x;
  const int t = threadIdx.x;
  const int s = offs[node];
  const int e = offs[node + 1];
  float acc[VEC];
#pragma unroll
  for (int k = 0; k < VEC; k++) acc[k] = 0.f;
  const size_t coloff = (size_t)t * VEC;
  int j = s;
  for (; j + 1 < e; j += 2) {
    int c0 = ecol[j], c1 = ecol[j + 1];
    float v0 = ev[j], v1 = ev[j + 1];
    const u16* p0 = X + (size_t)c0 * dcols + coloff;
    const u16* p1 = X + (size_t)c1 * dcols + coloff;
    if (VEC == 4) {
      ushort4 a = *(const ushort4*)p0;
      ushort4 b = *(const ushort4*)p1;
      acc[0] += v0 * b2f(a.x) + v1 * b2f(b.x);
      acc[1] += v0 * b2f(a.y) + v1 * b2f(b.y);
      acc[2] += v0 * b2f(a.z) + v1 * b2f(b.z);
      acc[3] += v0 * b2f(a.w) + v1 * b2f(b.w);
    } else {
      ushort2 a = *(const ushort2*)p0;
      ushort2 b = *(const ushort2*)p1;
      acc[0] += v0 * b2f(a.x) + v1 * b2f(b.x);
      acc[1] += v0 * b2f(a.y) + v1 * b2f(b.y);
    }
  }
  if (j < e) {
    int c0 = ecol[j];
    float v0 = ev[j];
    const u16* p0 = X + (size_t)c0 * dcols + coloff;
    if (VEC == 4) {
      ushort4 a = *(const ushort4*)p0;
      acc[0] += v0 * b2f(a.x);
      acc[1] += v0 * b2f(a.y);
      acc[2] += v0 * b2f(a.z);
      acc[3] += v0 * b2f(a.w);
    } else {
      ushort2 a = *(const ushort2*)p0;
      acc[0] += v0 * b2f(a.x);
      acc[1] += v0 * b2f(a.y);
    }
  }
#pragma unroll
  for (int k = 0; k < VEC; k++)
    if (RELU) acc[k] = fmaxf(acc[k], 0.f);
  if (OUTF32) {
    float* o = (float*)outp + (size_t)node * dcols + coloff;
    if (VEC == 4) {
      float4 st; st.x = acc[0]; st.y = acc[1]; st.z = acc[2]; st.w = acc[3];
      *(float4*)o = st;
    } else {
      float2 st; st.x = acc[0]; st.y = acc[1];
      *(float2*)o = st;
    }
  } else {
    u16* o = (u16*)outp + (size_t)node * dcols + coloff;
    if (VEC == 4) {
      ushort4 st; st.x = f2b(acc[0]); st.y = f2b(acc[1]); st.z = f2b(acc[2]); st.w = f2b(acc[3]);
      *(ushort4*)o = st;
    } else {
      ushort2 st; st.x = f2b(acc[0]); st.y = f2b(acc[1]);
      *(ushort2*)o = st;
    }
  }
}

extern "C" void kernel_launch(void* const* d_in, const int* in_sizes, int n_in,
                              void* d_out, int out_size, void* d_ws, size_t ws_size,
                              hipStream_t stream) {
  const float* fea = (const float*)d_in[0];
  const int* ei = (const int*)d_in[1];
  const float* ev = (const float*)d_in[2];
  const float* W1 = (const float*)d_in[3];
  const float* b1 = (const float*)d_in[4];
  const float* W2 = (const float*)d_in[5];
  const float* b2 = (const float*)d_in[6];
  const float* W3 = (const float*)d_in[7];
  const float* b3 = (const float*)d_in[8];
  const int E = in_sizes[1] / 2;
  const int* erow = ei;
  const int* ecol_in = ei + E;

  char* w = (char*)d_ws;
  auto alloc = [&](size_t bytes) {
    char* p = w;
    w += (bytes + 255) & ~(size_t)255;
    return p;
  };
  u16* fea_b = (u16*)alloc((size_t)NPAD * 1024 * 2);  // later reused as h2
  u16* bufB  = (u16*)alloc((size_t)NPAD * 1024 * 2);  // agg0, later t3
  u16* h1_b  = (u16*)alloc((size_t)NPAD * 2048 * 2);
  u16* t2_b  = (u16*)alloc((size_t)NPAD * 1024 * 2);
  u16* W1t = (u16*)alloc((size_t)2048 * 1024 * 2);
  u16* W2t = (u16*)alloc((size_t)1024 * 2048 * 2);
  u16* W3t = (u16*)alloc((size_t)512 * 1024 * 2);
  float* rowsum = (float*)alloc((size_t)NN * 4);
  int* counts = (int*)alloc((size_t)NN * 4);
  int* cursor = (int*)alloc((size_t)NN * 4);
  int* offs = (int*)alloc((size_t)(NN + 1) * 4);
  int* ecol = (int*)alloc((size_t)E * 4);
  float* ev2 = (float*)alloc((size_t)E * 4);
  int* bsum = (int*)alloc(256 * 4);
  (void)bsum; (void)ws_size; (void)n_in; (void)out_size;

  // zero rowsum, counts, cursor (contiguous region up to offs)
  hipMemsetAsync(rowsum, 0, (size_t)((char*)offs - (char*)rowsum), stream);

  const int eb = (E + 255) / 256;
  const int nb = (NN + 256) / 256;  // covers gi = NN inclusive
  hist_kernel<<<eb, 256, 0, stream>>>(erow, ev, counts, rowsum, E);
  scan_bsum<<<nb, 256, 0, stream>>>(counts, bsum, NN);
  scan_partials<<<1, 256, 0, stream>>>(bsum, nb);
  scan_final<<<nb, 256, 0, stream>>>(counts, bsum, offs, NN);
  scatter_kernel<<<eb, 256, 0, stream>>>(erow, ecol_in, ev, offs, cursor, ecol, ev2, E);

  conv_f2b4<<<(NN * 1024 / 4 + 255) / 256, 256, 0, stream>>>(fea, fea_b, NN * 1024 / 4);
  dim3 tb(32, 8);
  transpose_conv<<<dim3(2048 / 32, 1024 / 32), tb, 0, stream>>>(W1, W1t, 1024, 2048);
  transpose_conv<<<dim3(1024 / 32, 2048 / 32), tb, 0, stream>>>(W2, W2t, 2048, 1024);
  transpose_conv<<<dim3(512 / 32, 1024 / 32), tb, 0, stream>>>(W3, W3t, 1024, 512);

  const int MT = (NN + 127) / 128;  // 391
  // layer 1: agg0 = A @ fea ; h1 = relu(agg0 @ W1 + rowsum*b1)
  spmm<4, 0, 0><<<NN, 256, 0, stream>>>(offs, ecol, ev2, fea_b, bufB, 1024);
  gemm_bt<<<dim3(MT, 2048 / 128), 256, 0, stream>>>(bufB, W1t, b1, rowsum, h1_b, NN, 2048, 1024, 1);
  // layer 2: t2 = h1 @ W2 + b2 ; h2 = relu(A @ t2)
  gemm_bt<<<dim3(MT, 1024 / 128), 256, 0, stream>>>(h1_b, W2t, b2, nullptr, t2_b, NN, 1024, 2048, 0);
  spmm<4, 1, 0><<<NN, 256, 0, stream>>>(offs, ecol, ev2, t2_b, fea_b, 1024);
  // layer 3: t3 = h2 @ W3 + b3 ; out = A @ t3
  gemm_bt<<<dim3(MT, 512 / 128), 256, 0, stream>>>(fea_b, W3t, b3, nullptr, bufB, NN, 512, 1024, 0);
  spmm<2, 0, 1><<<NN, 256, 0, stream>>>(offs, ecol, ev2, bufB, d_out, 512);
}